// Round 5
// baseline (407.402 us; speedup 1.0000x reference)
//
#include <hip/hip_runtime.h>
#include <hip/hip_bf16.h>

typedef __bf16 bf16;
typedef bf16 bf16x2 __attribute__((ext_vector_type(2)));
typedef bf16 bf16x4 __attribute__((ext_vector_type(4)));
typedef bf16 bf16x8 __attribute__((ext_vector_type(8)));
typedef float floatx4 __attribute__((ext_vector_type(4)));

#define MFMA_BF16(a, b, c) __builtin_amdgcn_mfma_f32_16x16x32_bf16((a), (b), (c), 0, 0, 0)

// ---------------------------------------------------------------------------
// fp32 -> bf16 convert for BOTH x and ctx in one launch (8 els/thread).
// ---------------------------------------------------------------------------
__global__ __launch_bounds__(256) void cvt2_kernel(const float* __restrict__ x,
                                                   const float* __restrict__ ctx,
                                                   bf16* __restrict__ xb,
                                                   bf16* __restrict__ cb) {
    int idx = blockIdx.x * 256 + threadIdx.x;   // 0..1048575
    const float* in;
    bf16* out;
    int i;
    if (idx < 524288) { in = x; out = xb; i = idx; }
    else              { in = ctx; out = cb; i = idx - 524288; }
    const float* src = in + (size_t)i * 8;
    float4 f0 = *(const float4*)src;
    float4 f1 = *(const float4*)(src + 4);
    bf16x8 v = {(bf16)f0.x, (bf16)f0.y, (bf16)f0.z, (bf16)f0.w,
                (bf16)f1.x, (bf16)f1.y, (bf16)f1.z, (bf16)f1.w};
    *(bf16x8*)(out + (size_t)i * 8) = v;
}

// ---------------------------------------------------------------------------
// fp32 [1024][C] -> bf16 [C][1024] transpose for BOTH Wq (z=0) and Wkv (z=1).
// ---------------------------------------------------------------------------
__global__ __launch_bounds__(256) void trans2_kernel(const float* __restrict__ Wq,
                                                     const float* __restrict__ Wkv,
                                                     bf16* __restrict__ WqT,
                                                     bf16* __restrict__ WkvT) {
    const int z = blockIdx.z;
    if (z == 0 && blockIdx.x >= 32) return;
    const float* in = z ? Wkv : Wq;
    bf16* out = z ? WkvT : WqT;
    const int C = z ? 2048 : 1024, R = 1024;
    __shared__ float tile[32][33];
    const int t = threadIdx.x;
    const int r0 = blockIdx.y * 32, c0 = blockIdx.x * 32;
    int r = t >> 3, c4 = (t & 7) * 4;
    float4 v = *(const float4*)&in[(size_t)(r0 + r) * C + c0 + c4];
    tile[r][c4 + 0] = v.x; tile[r][c4 + 1] = v.y;
    tile[r][c4 + 2] = v.z; tile[r][c4 + 3] = v.w;
    __syncthreads();
    int rp = t >> 3, cp = (t & 7) * 4;
    bf16x4 w = {(bf16)tile[cp + 0][rp], (bf16)tile[cp + 1][rp],
                (bf16)tile[cp + 2][rp], (bf16)tile[cp + 3][rp]};
    *(bf16x4*)&out[(size_t)(c0 + rp) * R + r0 + cp] = w;
}

// ---------------------------------------------------------------------------
// Merged 128x128 GEMM: blockIdx.x<8 -> Q = xb @ WqT^T; else KV = cb @ WkvT^T.
// KV epilogue: n<1024 -> Kb[m][n]; n>=1024 -> Vt[b][h][d][j] directly (bf16x4).
// ---------------------------------------------------------------------------
__global__ __launch_bounds__(256) void gemm_all(const bf16* __restrict__ xb,
                                                const bf16* __restrict__ cb,
                                                const bf16* __restrict__ WqT,
                                                const bf16* __restrict__ WkvT,
                                                bf16* __restrict__ Qb,
                                                bf16* __restrict__ Kb,
                                                bf16* __restrict__ Vt) {
    __shared__ bf16 As[128 * 40];
    __shared__ bf16 Bs[128 * 40];
    const bool isQ = blockIdx.x < 8;
    const bf16* A = isQ ? xb : cb;
    const bf16* B = isQ ? WqT : WkvT;
    const int t = threadIdx.x;
    const int wv = t >> 6, lane = t & 63, quad = lane >> 4, l15 = lane & 15;
    const int wr = wv >> 1, wc = wv & 1;
    const int m0 = blockIdx.y * 128;
    const int n0 = (isQ ? blockIdx.x : blockIdx.x - 8) * 128;
    const int ra = t >> 1, kc = (t & 1) * 16;

    floatx4 acc[4][4] = {};

    for (int k0 = 0; k0 < 1024; k0 += 32) {
        bf16x8 a0 = *(const bf16x8*)&A[(size_t)(m0 + ra) * 1024 + k0 + kc];
        bf16x8 a1 = *(const bf16x8*)&A[(size_t)(m0 + ra) * 1024 + k0 + kc + 8];
        bf16x8 b0 = *(const bf16x8*)&B[(size_t)(n0 + ra) * 1024 + k0 + kc];
        bf16x8 b1 = *(const bf16x8*)&B[(size_t)(n0 + ra) * 1024 + k0 + kc + 8];
        __syncthreads();
        *(bf16x8*)&As[ra * 40 + kc] = a0;
        *(bf16x8*)&As[ra * 40 + kc + 8] = a1;
        *(bf16x8*)&Bs[ra * 40 + kc] = b0;
        *(bf16x8*)&Bs[ra * 40 + kc + 8] = b1;
        __syncthreads();
        bf16x8 af[4], bfr[4];
#pragma unroll
        for (int mt = 0; mt < 4; ++mt)
            af[mt] = *(bf16x8*)&As[(wr * 64 + mt * 16 + l15) * 40 + quad * 8];
#pragma unroll
        for (int nt = 0; nt < 4; ++nt)
            bfr[nt] = *(bf16x8*)&Bs[(wc * 64 + nt * 16 + l15) * 40 + quad * 8];
#pragma unroll
        for (int mt = 0; mt < 4; ++mt)
#pragma unroll
            for (int nt = 0; nt < 4; ++nt)
                acc[mt][nt] = MFMA_BF16(af[mt], bfr[nt], acc[mt][nt]);
    }
#pragma unroll
    for (int mt = 0; mt < 4; ++mt)
#pragma unroll
        for (int nt = 0; nt < 4; ++nt) {
            int mb = m0 + wr * 64 + mt * 16 + quad * 4;  // m for r=0 (4-aligned run)
            int n = n0 + wc * 64 + nt * 16 + l15;
            if (isQ) {
#pragma unroll
                for (int r = 0; r < 4; ++r)
                    Qb[(size_t)(mb + r) * 1024 + n] = (bf16)acc[mt][nt][r];
            } else if (n < 1024) {
#pragma unroll
                for (int r = 0; r < 4; ++r)
                    Kb[(size_t)(mb + r) * 1024 + n] = (bf16)acc[mt][nt][r];
            } else {
                int nn = n - 1024, h = nn >> 6, d = nn & 63;
                int bb = mb >> 10, j = mb & 1023;
                bf16x4 v4 = {(bf16)acc[mt][nt][0], (bf16)acc[mt][nt][1],
                             (bf16)acc[mt][nt][2], (bf16)acc[mt][nt][3]};
                *(bf16x4*)&Vt[(size_t)((bb * 16 + h) * 64 + d) * 1024 + j] = v4;
            }
        }
}

// ---------------------------------------------------------------------------
// Softmax denominators: L[b][h][i] = sum_j exp(q.k*scale).
// grid (i32=32, b=4, jsplit=8), 256 thr = 4 waves, 4 heads/wave; head loop
// outer so only one head's Q frags live (no launch-bounds cap -> no spills).
// ---------------------------------------------------------------------------
__global__ __launch_bounds__(256) void denom_kernel(const bf16* __restrict__ Qb,
                                                    const bf16* __restrict__ Kb,
                                                    float* __restrict__ L) {
    const int t = threadIdx.x;
    const int wv = t >> 6, lane = t & 63, quad = lane >> 4, l15 = lane & 15;
    const int i0 = blockIdx.x * 32, b = blockIdx.y, jz = blockIdx.z;
    const float scale = 0.125f;
    const bf16* Kbase = Kb + (size_t)b * 1024 * 1024;

    for (int hh = 0; hh < 4; ++hh) {
        const int h = wv * 4 + hh;
        bf16x8 qa[2][2];
#pragma unroll
        for (int it = 0; it < 2; ++it) {
            const bf16* qp = Qb + (size_t)(b * 1024 + i0 + it * 16 + l15) * 1024 +
                             h * 64 + quad * 8;
            qa[it][0] = *(const bf16x8*)qp;
            qa[it][1] = *(const bf16x8*)(qp + 32);
        }
        floatx4 se[2] = {};
#pragma unroll
        for (int jt = 0; jt < 8; ++jt) {
            int j = jz * 128 + jt * 16 + l15;
            const bf16* kp = Kbase + (size_t)j * 1024 + h * 64 + quad * 8;
            bf16x8 k0 = *(const bf16x8*)kp;
            bf16x8 k1 = *(const bf16x8*)(kp + 32);
#pragma unroll
            for (int it = 0; it < 2; ++it) {
                floatx4 c = {0.f, 0.f, 0.f, 0.f};
                c = MFMA_BF16(qa[it][0], k0, c);
                c = MFMA_BF16(qa[it][1], k1, c);
#pragma unroll
                for (int r = 0; r < 4; ++r) se[it][r] += __expf(c[r] * scale);
            }
        }
#pragma unroll
        for (int it = 0; it < 2; ++it)
#pragma unroll
            for (int r = 0; r < 4; ++r) {
                float s = se[it][r];
                s += __shfl_xor(s, 1); s += __shfl_xor(s, 2);
                s += __shfl_xor(s, 4); s += __shfl_xor(s, 8);
                if (l15 == 0)
                    atomicAdd(&L[(size_t)(b * 16 + h) * 1024 + i0 + it * 16 +
                                 quad * 4 + r], s);
            }
    }
}

// ---------------------------------------------------------------------------
// mixw: fully wave-independent scores -> softmax -> talking-heads mix -> LN ->
// materialized Wf[bl][g][i][j] (bf16). Key trick: S computed TRANSPOSED
// (A=K[m=j], B=Q[n=i]) so each lane holds (j=quad*4+r, i=l15) for ALL 16
// heads -> mix is in-lane VALU FMA with Wt_centered broadcast from LDS;
// LN over heads is in-lane; invl[h] per-lane (i fixed). No barriers in loop.
// task = blockIdx.x*4+wv: jz=task&7 (128-wide j slice), it=(task>>3)&63,
// bl=task>>9 (local batch index).
// ---------------------------------------------------------------------------
__global__ __launch_bounds__(256) void mixw_kernel(const bf16* __restrict__ Qb,
                                                   const bf16* __restrict__ Kb,
                                                   const float* __restrict__ L,
                                                   const float* __restrict__ Wt,
                                                   const float* __restrict__ gamma,
                                                   const float* __restrict__ beta,
                                                   bf16* __restrict__ Wf,
                                                   int b_base, int g0, int gcnt) {
    __shared__ float WtcLDS[256];
    const int t = threadIdx.x;
    {   // centered Wt: Wtc[h][g] = Wt[h][g] - mean_g(Wt[h][:])
        int h = t >> 4, g = t & 15;
        float s = 0.f;
#pragma unroll
        for (int gg = 0; gg < 16; ++gg) s += Wt[h * 16 + gg];
        WtcLDS[t] = Wt[h * 16 + g] - s * 0.0625f;
    }
    __syncthreads();

    const int wv = t >> 6, lane = t & 63, quad = lane >> 4, l15 = lane & 15;
    const int task = blockIdx.x * 4 + wv;
    const int jz = task & 7, it = (task >> 3) & 63, bl = task >> 9;
    const int b = b_base + bl, i0 = it * 16;
    const float scale = 0.125f;

    float invl[16];
#pragma unroll
    for (int h = 0; h < 16; ++h)
        invl[h] = 1.f / L[(size_t)(b * 16 + h) * 1024 + i0 + l15];

    const bf16* Qp0 = Qb + (size_t)(b * 1024 + i0 + l15) * 1024 + quad * 8;
    const bf16* Kbase = Kb + (size_t)(b * 1024) * 1024 + quad * 8;

    for (int jt = 0; jt < 8; ++jt) {
        const int j0 = jz * 128 + jt * 16;
        const bf16* Kp0 = Kbase + (size_t)(j0 + l15) * 1024;
        floatx4 wmix[16];
#pragma unroll
        for (int g = 0; g < 16; ++g) wmix[g] = (floatx4){0.f, 0.f, 0.f, 0.f};

        for (int h = 0; h < 16; ++h) {
            bf16x8 aK0 = *(const bf16x8*)(Kp0 + h * 64);
            bf16x8 aK1 = *(const bf16x8*)(Kp0 + h * 64 + 32);
            bf16x8 bQ0 = *(const bf16x8*)(Qp0 + h * 64);
            bf16x8 bQ1 = *(const bf16x8*)(Qp0 + h * 64 + 32);
            floatx4 c = {0.f, 0.f, 0.f, 0.f};
            c = MFMA_BF16(aK0, bQ0, c);
            c = MFMA_BF16(aK1, bQ1, c);
            floatx4 p;
#pragma unroll
            for (int r = 0; r < 4; ++r) p[r] = __expf(c[r] * scale) * invl[h];
#pragma unroll
            for (int g = 0; g < 16; ++g) {
                float wc = WtcLDS[h * 16 + g];
                wmix[g] += p * wc;
            }
        }
        floatx4 s2 = {0.f, 0.f, 0.f, 0.f};
#pragma unroll
        for (int g = 0; g < 16; ++g) s2 += wmix[g] * wmix[g];
        floatx4 rs;
#pragma unroll
        for (int r = 0; r < 4; ++r) rs[r] = rsqrtf(s2[r] * 0.0625f + 1e-5f);
#pragma unroll
        for (int g = 0; g < 16; ++g) {
            if (g < g0 || g >= g0 + gcnt) continue;
            float gm = gamma[g], bt = beta[g];
            bf16x4 v;
#pragma unroll
            for (int r = 0; r < 4; ++r) v[r] = (bf16)(wmix[g][r] * rs[r] * gm + bt);
            *(bf16x4*)&Wf[((size_t)((bl * gcnt + (g - g0)) * 1024 + i0 + l15)) * 1024 +
                          j0 + quad * 4] = v;
        }
    }
}

// ---------------------------------------------------------------------------
// pv: batched GEMM O[b,g,i,d] = sum_j Wf[g,i,j] * V[g,j,d]. A-frags straight
// from Wf (m=i, k=j), B-frags from Vt[b][g][d][j] (n=d, k=j). No atomics;
// out written exactly once. task = blockIdx.x*4+wv: it=task&63,
// gl=(task>>6)&(gcnt-1), bl=task>>(6+gshift).
// ---------------------------------------------------------------------------
__global__ __launch_bounds__(256) void pv_kernel(const bf16* __restrict__ Wf,
                                                 const bf16* __restrict__ Vt,
                                                 float* __restrict__ out,
                                                 int b_base, int g0, int gshift) {
    const int t = threadIdx.x;
    const int wv = t >> 6, lane = t & 63, quad = lane >> 4, l15 = lane & 15;
    const int gcnt = 1 << gshift;
    const int task = blockIdx.x * 4 + wv;
    const int it = task & 63, gl = (task >> 6) & (gcnt - 1), bl = task >> (6 + gshift);
    const int b = b_base + bl, g = g0 + gl, i0 = it * 16;

    const bf16* Wrow = Wf + ((size_t)((bl * gcnt + gl) * 1024 + i0 + l15)) * 1024 + quad * 8;
    const bf16* Vbase = Vt + (size_t)((b * 16 + g) * 64) * 1024 + quad * 8;
    floatx4 o[4] = {};

    for (int c32 = 0; c32 < 32; ++c32) {
        const int j0 = c32 * 32;
        bf16x8 aW = *(const bf16x8*)(Wrow + j0);
#pragma unroll
        for (int dt = 0; dt < 4; ++dt) {
            bf16x8 bV = *(const bf16x8*)(Vbase + (size_t)(dt * 16 + l15) * 1024 + j0);
            o[dt] = MFMA_BF16(aW, bV, o[dt]);
        }
    }
#pragma unroll
    for (int dt = 0; dt < 4; ++dt)
#pragma unroll
        for (int r = 0; r < 4; ++r)
            out[(size_t)(b * 1024 + i0 + quad * 4 + r) * 1024 + g * 64 + dt * 16 + l15] =
                o[dt][r];
}

extern "C" void kernel_launch(void* const* d_in, const int* in_sizes, int n_in,
                              void* d_out, int out_size, void* d_ws, size_t ws_size,
                              hipStream_t stream) {
    const float* x     = (const float*)d_in[0];
    const float* ctx   = (const float*)d_in[1];
    const float* Wq    = (const float*)d_in[2];
    const float* Wkv   = (const float*)d_in[3];
    const float* Wt    = (const float*)d_in[4];
    const float* gamma = (const float*)d_in[5];
    const float* beta  = (const float*)d_in[6];
    float* out = (float*)d_out;

    const size_t MI = 1024 * 1024;
    // ws layout (bf16 els): xb 4M | cb 4M | WqT 1M | WkvT 2M | Qb 4M | Kb 4M |
    //                       Vt 4M | L (64K fp32) | Wf (tiered)
    bf16* xb   = (bf16*)d_ws;
    bf16* cb   = xb + 4 * MI;
    bf16* WqT  = cb + 4 * MI;
    bf16* WkvT = WqT + 1 * MI;
    bf16* Qb   = WkvT + 2 * MI;
    bf16* Kb   = Qb + 4 * MI;
    bf16* Vt   = Kb + 4 * MI;
    float* L   = (float*)(Vt + 4 * MI);
    bf16* Wf   = (bf16*)(L + 64 * 1024);

    const size_t base_bytes = (size_t)23 * MI * 2 + 64 * 1024 * 4;  // ~46.25 MB

    hipMemsetAsync(L, 0, (size_t)64 * 1024 * sizeof(float), stream);

    cvt2_kernel<<<4096, 256, 0, stream>>>(x, ctx, xb, cb);
    trans2_kernel<<<dim3(64, 32, 2), 256, 0, stream>>>(Wq, Wkv, WqT, WkvT);
    gemm_all<<<dim3(24, 32), 256, 0, stream>>>(xb, cb, WqT, WkvT, Qb, Kb, Vt);
    denom_kernel<<<dim3(32, 4, 8), 256, 0, stream>>>(Qb, Kb, L);

    if (ws_size >= base_bytes + (size_t)64 * MI * 2) {
        // full Wf: 4b x 16g x 1024 x 1024 bf16 = 128 MiB
        mixw_kernel<<<512, 256, 0, stream>>>(Qb, Kb, L, Wt, gamma, beta, Wf, 0, 0, 16);
        pv_kernel<<<1024, 256, 0, stream>>>(Wf, Vt, out, 0, 0, 4);
    } else if (ws_size >= base_bytes + (size_t)16 * MI * 2) {
        // per-b batches: Wf 16g x 1M = 32 MiB reused
        for (int b = 0; b < 4; ++b) {
            mixw_kernel<<<128, 256, 0, stream>>>(Qb, Kb, L, Wt, gamma, beta, Wf, b, 0, 16);
            pv_kernel<<<256, 256, 0, stream>>>(Wf, Vt, out, b, 0, 4);
        }
    } else {
        // per-(b, half-heads): Wf 8g x 1M = 16 MiB reused
        for (int b = 0; b < 4; ++b)
            for (int gh = 0; gh < 16; gh += 8) {
                mixw_kernel<<<128, 256, 0, stream>>>(Qb, Kb, L, Wt, gamma, beta, Wf, b, gh, 8);
                pv_kernel<<<128, 256, 0, stream>>>(Wf, Vt, out, b, gh, 3);
            }
    }
}